// Round 2
// baseline (427.352 us; speedup 1.0000x reference)
//
#include <hip/hip_runtime.h>
#include <cstdint>
#include <climits>

#define EPSF 1e-7f
#define NCELL 1000          // 10x10x10 cells per batch, cell size 0.1 = radius
#define RPAD 0.10002f       // radius + fuzz for f32 binning boundary safety

__device__ __forceinline__ int cell_of(float x, float y, float z) {
    int cx = min(max((int)(x * 10.0f), 0), 9);
    int cy = min(max((int)(y * 10.0f), 0), 9);
    int cz = min(max((int)(z * 10.0f), 0), 9);
    return (cx * 10 + cy) * 10 + cz;
}

// ---------------------------------------------------------------------------
// K1: (a) per-face normal scattered into per-vertex accumulators (atomics);
//     (b) per-vertex grid-cell histogram (atomics). Independent, fused.
// ---------------------------------------------------------------------------
__global__ void k1_face_count(const float* __restrict__ hs,
                              const int* __restrict__ hf,
                              float* __restrict__ svec,
                              float* __restrict__ scnt,
                              int* __restrict__ counts,
                              int n_v, int n_f, int bs) {
    int t = blockIdx.x * blockDim.x + threadIdx.x;
    if (t < bs * n_f) {
        int b = t / n_f;
        int f = t - b * n_f;
        const int* fb = hf + (size_t)b * 3 * n_f;
        int i0 = fb[f];
        int i1 = fb[n_f + f];
        int i2 = fb[2 * n_f + f];
        const float* xs = hs + (size_t)b * 6 * n_v;
        const float* ys = xs + n_v;
        const float* zs = xs + 2 * n_v;
        float ax = xs[i0], ay = ys[i0], az = zs[i0];
        float bx = xs[i1], by = ys[i1], bz = zs[i1];
        float cx = xs[i2], cy = ys[i2], cz = zs[i2];
        float e1x = bx - ax, e1y = by - ay, e1z = bz - az;
        float e2x = cx - ax, e2y = cy - ay, e2z = cz - az;
        float fx = e1y * e2z - e1z * e2y;
        float fy = e1z * e2x - e1x * e2z;
        float fz = e1x * e2y - e1y * e2x;
        float nrm = sqrtf(fx * fx + fy * fy + fz * fz) + EPSF;
        fx /= nrm; fy /= nrm; fz /= nrm;
        float* sb = svec + (size_t)b * n_v * 3;
        float* cb = scnt + (size_t)b * n_v;
        int idx3[3] = {i0, i1, i2};
        #pragma unroll
        for (int k = 0; k < 3; ++k) {
            int i = idx3[k];
            atomicAdd(&sb[i * 3 + 0], fx);
            atomicAdd(&sb[i * 3 + 1], fy);
            atomicAdd(&sb[i * 3 + 2], fz);
            atomicAdd(&cb[i], 1.0f);
        }
    }
    if (t < bs * n_v) {
        int b = t / n_v;
        int v = t - b * n_v;
        const float* xs = hs + (size_t)b * 6 * n_v;
        float x = xs[v], y = xs[n_v + v], z = xs[2 * n_v + v];
        atomicAdd(&counts[b * NCELL + cell_of(x, y, z)], 1);
    }
}

// ---------------------------------------------------------------------------
// K2: blocks [0, nvb): vertex unit normals in-place over svec.
//     block nvb: exclusive prefix scan of both batches' cell histograms
//     (one wave per batch, 16 cells/lane, shuffle scan). Writes cellstart
//     (1001 entries/batch) and cursor (scatter write heads).
// ---------------------------------------------------------------------------
__global__ void k2_vn_scan(float* __restrict__ svec,
                           const float* __restrict__ scnt,
                           const int* __restrict__ counts,
                           int* __restrict__ cellstart,
                           int* __restrict__ cursor,
                           int total_v, int nvb) {
    if (blockIdx.x < (unsigned)nvb) {
        int t = blockIdx.x * blockDim.x + threadIdx.x;
        if (t >= total_v) return;
        float cc = scnt[t] + EPSF;
        float vx = svec[t * 3 + 0] / cc;
        float vy = svec[t * 3 + 1] / cc;
        float vz = svec[t * 3 + 2] / cc;
        float nrm = sqrtf(vx * vx + vy * vy + vz * vz) + EPSF;
        svec[t * 3 + 0] = vx / nrm;
        svec[t * 3 + 1] = vy / nrm;
        svec[t * 3 + 2] = vz / nrm;
        return;
    }
    // scan block: threads 0..63 = batch 0, 64..127 = batch 1
    if (threadIdx.x >= 128) return;
    int batch = threadIdx.x >> 6;
    int lane = threadIdx.x & 63;
    int local[16];
    int mysum = 0;
    #pragma unroll
    for (int k = 0; k < 16; ++k) {
        int c = lane * 16 + k;
        int v = (c < NCELL) ? counts[batch * NCELL + c] : 0;
        local[k] = v;
        mysum += v;
    }
    int s = mysum;
    #pragma unroll
    for (int off = 1; off < 64; off <<= 1) {
        int n = __shfl_up(s, off);
        if (lane >= off) s += n;
    }
    int excl = s - mysum;
    #pragma unroll
    for (int k = 0; k < 16; ++k) {
        int c = lane * 16 + k;
        if (c < NCELL) {
            cellstart[batch * (NCELL + 1) + c] = excl;
            cursor[batch * NCELL + c] = excl;
            excl += local[k];
        }
    }
    if (lane == 63) cellstart[batch * (NCELL + 1) + NCELL] = s;
}

// ---------------------------------------------------------------------------
// K3: scatter vertices into cell-sorted float4(x,y,z,bitcast(id)) array.
// ---------------------------------------------------------------------------
__global__ void k3_scatter(const float* __restrict__ hs,
                           int* __restrict__ cursor,
                           float4* __restrict__ spk,
                           int n_v, int bs) {
    int t = blockIdx.x * blockDim.x + threadIdx.x;
    if (t >= bs * n_v) return;
    int b = t / n_v;
    int v = t - b * n_v;
    const float* xs = hs + (size_t)b * 6 * n_v;
    float x = xs[v], y = xs[n_v + v], z = xs[2 * n_v + v];
    int cell = cell_of(x, y, z);
    int pos = atomicAdd(&cursor[b * NCELL + cell], 1);
    spk[(size_t)b * n_v + pos] = make_float4(x, y, z, __int_as_float(v));
}

// ---------------------------------------------------------------------------
// K4: one wave per query. Walk <=27 grid cells (9 z-contiguous runs), lanes
// test candidates in parallel (one 16B load each), per-lane sorted min-4 of
// hit ids, then 4-round cross-lane min extraction = the 4 smallest in-radius
// vertex ids == ball-query's "first NSAMPLE in index order". Epilogue is the
// round-1 (bit-exact) loss math. Block partial -> deterministic last-block
// finalize via done-counter.
// ---------------------------------------------------------------------------
__global__ void k4_query(const float* __restrict__ pred,
                         const float* __restrict__ hs,
                         const float* __restrict__ un,
                         const float4* __restrict__ spk,
                         const int* __restrict__ cellstart,
                         double* __restrict__ partial,
                         float* __restrict__ pcnt,
                         int* __restrict__ done,
                         float* __restrict__ out,
                         int n_v, int n_pred, int bs) {
    const int lane = threadIdx.x & 63;
    const int wave = threadIdx.x >> 6;
    const int wid = blockIdx.x * 4 + wave;
    const int nq = bs * n_pred;

    float per_pt = 0.0f;
    float is_pos = 0.0f;

    if (wid < nq) {
        const int b = wid / n_pred;
        const float* xs = hs + (size_t)b * 6 * n_v;
        const float* ys = xs + n_v;
        const float* zs = xs + 2 * n_v;
        const float* unb = un + (size_t)b * n_v * 3;
        const float4* sp = spk + (size_t)b * n_v;
        const int* csb = cellstart + b * (NCELL + 1);
        const float px = pred[(size_t)wid * 3 + 0];
        const float py = pred[(size_t)wid * 3 + 1];
        const float pz = pred[(size_t)wid * 3 + 2];

        int xlo = max(0, (int)floorf((px - RPAD) * 10.0f));
        int xhi = min(9, (int)floorf((px + RPAD) * 10.0f));
        int ylo = max(0, (int)floorf((py - RPAD) * 10.0f));
        int yhi = min(9, (int)floorf((py + RPAD) * 10.0f));
        int zlo = max(0, (int)floorf((pz - RPAD) * 10.0f));
        int zhi = min(9, (int)floorf((pz + RPAD) * 10.0f));

        int l0 = INT_MAX, l1 = INT_MAX, l2 = INT_MAX, l3 = INT_MAX;
        for (int cx = xlo; cx <= xhi; ++cx) {
            for (int cy = ylo; cy <= yhi; ++cy) {
                int rowbase = (cx * 10 + cy) * 10;
                int rs = csb[rowbase + zlo];
                int re = csb[rowbase + zhi + 1];
                for (int p = rs + lane; p < re; p += 64) {
                    float4 c4 = sp[p];
                    float dx = px - c4.x;
                    float dy = py - c4.y;
                    float dz = pz - c4.z;
                    float d2 = dx * dx + dy * dy + dz * dz;
                    if (d2 < 0.01f) {     // 0.01f == f32(0.1*0.1)
                        int vid = __float_as_int(c4.w);
                        if (vid < l3) {
                            if (vid < l1) {
                                if (vid < l0) { l3 = l2; l2 = l1; l1 = l0; l0 = vid; }
                                else          { l3 = l2; l2 = l1; l1 = vid; }
                            } else {
                                if (vid < l2) { l3 = l2; l2 = vid; }
                                else          { l3 = vid; }
                            }
                        }
                    }
                }
            }
        }

        // 4-round cross-lane min extraction (ids unique -> exactly one owner)
        int a0 = l0, a1 = l1, a2 = l2, a3 = l3;
        int s0, s1, s2, s3;
        #pragma unroll
        for (int j = 0; j < 4; ++j) {
            int m = a0;
            #pragma unroll
            for (int off = 1; off < 64; off <<= 1) m = min(m, __shfl_xor(m, off));
            if (j == 0) s0 = m; else if (j == 1) s1 = m; else if (j == 2) s2 = m; else s3 = m;
            if (a0 == m && m != INT_MAX) { a0 = a1; a1 = a2; a2 = a3; a3 = INT_MAX; }
        }
        int id0 = (s0 == INT_MAX) ? 0 : s0;      // no hits -> index 0 (ref argmax)
        int id1 = (s1 == INT_MAX) ? id0 : s1;    // unfilled -> first hit
        int id2 = (s2 == INT_MAX) ? id0 : s2;
        int id3 = (s3 == INT_MAX) ? id0 : s3;
        int ids[4] = {id0, id1, id2, id3};

        float vd[4];
        float cm = 0.0f;
        #pragma unroll
        for (int j = 0; j < 4; ++j) {
            int id = ids[j];
            float dx = px - xs[id];
            float dy = py - ys[id];
            float dz = pz - zs[id];
            float nx = unb[id * 3 + 0];
            float ny = unb[id * 3 + 1];
            float nz = unb[id * 3 + 2];
            float dot = dx * nx + dy * ny + dz * nz;
            float w = (dot >= -0.1f) ? 1.0f : 0.0f;
            float v = (dot - 0.001f) * w;
            bool msk = v < 0.0f;
            vd[j] = msk ? v : 0.0f;
            cm += msk ? 1.0f : 0.0f;
        }
        float s = ((vd[0] + vd[1]) + vd[2]) + vd[3];
        float a = s / (cm + EPSF);
        per_pt = a * a;
        is_pos = (per_pt > 0.0f) ? 1.0f : 0.0f;
    }

    __shared__ float ls[4];
    __shared__ float lc[4];
    if (lane == 0) { ls[wave] = per_pt; lc[wave] = is_pos; }
    __syncthreads();
    if (threadIdx.x == 0) {
        partial[blockIdx.x] = (double)ls[0] + (double)ls[1] + (double)ls[2] + (double)ls[3];
        pcnt[blockIdx.x] = ((lc[0] + lc[1]) + lc[2]) + lc[3];
    }
    __threadfence();
    __shared__ int lastflag;
    if (threadIdx.x == 0) lastflag = (atomicAdd(done, 1) == (int)gridDim.x - 1) ? 1 : 0;
    __syncthreads();
    if (lastflag) {
        __threadfence();  // acquire: see all other blocks' partial writes
        double s = 0.0, c = 0.0;
        for (int i = threadIdx.x; i < (int)gridDim.x; i += blockDim.x) {
            s += partial[i];
            c += (double)pcnt[i];
        }
        #pragma unroll
        for (int off = 32; off > 0; off >>= 1) {
            s += __shfl_down(s, off);
            c += __shfl_down(c, off);
        }
        __shared__ double ds[4];
        __shared__ double dc[4];
        if (lane == 0) { ds[wave] = s; dc[wave] = c; }
        __syncthreads();
        if (threadIdx.x == 0) {
            double S = ds[0] + ds[1] + ds[2] + ds[3];
            double C = dc[0] + dc[1] + dc[2] + dc[3];
            out[0] = (float)(S / (C + 1e-7));
        }
    }
}

extern "C" void kernel_launch(void* const* d_in, const int* in_sizes, int n_in,
                              void* d_out, int out_size, void* d_ws, size_t ws_size,
                              hipStream_t stream) {
    const float* pred    = (const float*)d_in[0];
    const float* h_state = (const float*)d_in[2];
    const int*   h_faces = (const int*)d_in[3];
    float* out = (float*)d_out;

    const int bs = 2;
    const int n_pred = in_sizes[0] / (bs * 3);   // 8192
    const int n_v    = in_sizes[2] / (bs * 6);   // 6890
    const int n_f    = in_sizes[3] / (bs * 3);   // 13776
    const int nq = bs * n_pred;                  // 16384
    const int nblk = (nq + 3) / 4;               // 4096 blocks, 4 queries each

    // ---- workspace layout (float-element offsets from d_ws) ----
    size_t o_svec    = 0;                                  // bs*n_v*3 f (zeroed)
    size_t o_scnt    = o_svec + (size_t)bs * n_v * 3;      // bs*n_v f  (zeroed)
    size_t o_counts  = o_scnt + (size_t)bs * n_v;          // bs*1000 i (zeroed)
    size_t o_done    = o_counts + (size_t)bs * NCELL;      // 1 i       (zeroed)
    size_t o_zeroend = (o_done + 1 + 3) & ~(size_t)3;      // pad to 16B
    size_t o_cursor  = o_zeroend;                          // bs*1000 i
    size_t o_cs      = o_cursor + (size_t)bs * NCELL;      // bs*1001 i
    size_t o_partial = (o_cs + (size_t)bs * (NCELL + 1) + 1) & ~(size_t)1; // nblk d
    size_t o_pcnt    = o_partial + 2 * (size_t)nblk;       // nblk f
    size_t o_spk     = (o_pcnt + (size_t)nblk + 3) & ~(size_t)3;           // bs*n_v f4

    float* base = (float*)d_ws;
    float*  svec      = base + o_svec;
    float*  scnt      = base + o_scnt;
    int*    counts    = (int*)(base + o_counts);
    int*    done      = (int*)(base + o_done);
    int*    cursor    = (int*)(base + o_cursor);
    int*    cellstart = (int*)(base + o_cs);
    double* partial   = (double*)(base + o_partial);
    float*  pcnt      = base + o_pcnt;
    float4* spk       = (float4*)(base + o_spk);

    // zero the accumulator zone (svec, scnt, counts, done) in one memset
    hipMemsetAsync(d_ws, 0, o_zeroend * sizeof(float), stream);

    int t1 = bs * n_f;   // >= bs*n_v, covers both fused jobs
    k1_face_count<<<(t1 + 255) / 256, 256, 0, stream>>>(
        h_state, h_faces, svec, scnt, counts, n_v, n_f, bs);

    int nvb = (bs * n_v + 255) / 256;
    k2_vn_scan<<<nvb + 1, 256, 0, stream>>>(
        svec, scnt, counts, cellstart, cursor, bs * n_v, nvb);

    k3_scatter<<<(bs * n_v + 255) / 256, 256, 0, stream>>>(
        h_state, cursor, spk, n_v, bs);

    k4_query<<<nblk, 256, 0, stream>>>(
        pred, h_state, svec, spk, cellstart, partial, pcnt, done, out,
        n_v, n_pred, bs);
}

// Round 3
// 111.219 us; speedup vs baseline: 3.8424x; 3.8424x over previous
//
#include <hip/hip_runtime.h>
#include <cstdint>
#include <climits>

#define EPSF 1e-7f
#define NCELL 1000          // 10x10x10 cells per batch, cell size 0.1 = radius
#define RPAD 0.10002f       // radius + fuzz for f32 binning boundary safety

__device__ __forceinline__ int cell_of(float x, float y, float z) {
    int cx = min(max((int)(x * 10.0f), 0), 9);
    int cy = min(max((int)(y * 10.0f), 0), 9);
    int cz = min(max((int)(z * 10.0f), 0), 9);
    return (cx * 10 + cy) * 10 + cz;
}

// ---------------------------------------------------------------------------
// K1: (a) per-face normal scattered into per-vertex accumulators (atomics);
//     (b) per-vertex grid-cell histogram (atomics). Independent, fused.
// ---------------------------------------------------------------------------
__global__ void k1_face_count(const float* __restrict__ hs,
                              const int* __restrict__ hf,
                              float* __restrict__ svec,
                              float* __restrict__ scnt,
                              int* __restrict__ counts,
                              int n_v, int n_f, int bs) {
    int t = blockIdx.x * blockDim.x + threadIdx.x;
    if (t < bs * n_f) {
        int b = t / n_f;
        int f = t - b * n_f;
        const int* fb = hf + (size_t)b * 3 * n_f;
        int i0 = fb[f];
        int i1 = fb[n_f + f];
        int i2 = fb[2 * n_f + f];
        const float* xs = hs + (size_t)b * 6 * n_v;
        const float* ys = xs + n_v;
        const float* zs = xs + 2 * n_v;
        float ax = xs[i0], ay = ys[i0], az = zs[i0];
        float bx = xs[i1], by = ys[i1], bz = zs[i1];
        float cx = xs[i2], cy = ys[i2], cz = zs[i2];
        float e1x = bx - ax, e1y = by - ay, e1z = bz - az;
        float e2x = cx - ax, e2y = cy - ay, e2z = cz - az;
        float fx = e1y * e2z - e1z * e2y;
        float fy = e1z * e2x - e1x * e2z;
        float fz = e1x * e2y - e1y * e2x;
        float nrm = sqrtf(fx * fx + fy * fy + fz * fz) + EPSF;
        fx /= nrm; fy /= nrm; fz /= nrm;
        float* sb = svec + (size_t)b * n_v * 3;
        float* cb = scnt + (size_t)b * n_v;
        int idx3[3] = {i0, i1, i2};
        #pragma unroll
        for (int k = 0; k < 3; ++k) {
            int i = idx3[k];
            atomicAdd(&sb[i * 3 + 0], fx);
            atomicAdd(&sb[i * 3 + 1], fy);
            atomicAdd(&sb[i * 3 + 2], fz);
            atomicAdd(&cb[i], 1.0f);
        }
    }
    if (t < bs * n_v) {
        int b = t / n_v;
        int v = t - b * n_v;
        const float* xs = hs + (size_t)b * 6 * n_v;
        float x = xs[v], y = xs[n_v + v], z = xs[2 * n_v + v];
        atomicAdd(&counts[b * NCELL + cell_of(x, y, z)], 1);
    }
}

// ---------------------------------------------------------------------------
// K2: blocks [0, nvb): vertex unit normals in-place over svec.
//     block nvb: exclusive prefix scan of both batches' cell histograms
//     (one wave per batch, 16 cells/lane, shuffle scan). Writes cellstart
//     (1001 entries/batch) and cursor (scatter write heads).
// ---------------------------------------------------------------------------
__global__ void k2_vn_scan(float* __restrict__ svec,
                           const float* __restrict__ scnt,
                           const int* __restrict__ counts,
                           int* __restrict__ cellstart,
                           int* __restrict__ cursor,
                           int total_v, int nvb) {
    if (blockIdx.x < (unsigned)nvb) {
        int t = blockIdx.x * blockDim.x + threadIdx.x;
        if (t >= total_v) return;
        float cc = scnt[t] + EPSF;
        float vx = svec[t * 3 + 0] / cc;
        float vy = svec[t * 3 + 1] / cc;
        float vz = svec[t * 3 + 2] / cc;
        float nrm = sqrtf(vx * vx + vy * vy + vz * vz) + EPSF;
        svec[t * 3 + 0] = vx / nrm;
        svec[t * 3 + 1] = vy / nrm;
        svec[t * 3 + 2] = vz / nrm;
        return;
    }
    // scan block: threads 0..63 = batch 0, 64..127 = batch 1
    if (threadIdx.x >= 128) return;
    int batch = threadIdx.x >> 6;
    int lane = threadIdx.x & 63;
    int local[16];
    int mysum = 0;
    #pragma unroll
    for (int k = 0; k < 16; ++k) {
        int c = lane * 16 + k;
        int v = (c < NCELL) ? counts[batch * NCELL + c] : 0;
        local[k] = v;
        mysum += v;
    }
    int s = mysum;
    #pragma unroll
    for (int off = 1; off < 64; off <<= 1) {
        int n = __shfl_up(s, off);
        if (lane >= off) s += n;
    }
    int excl = s - mysum;
    #pragma unroll
    for (int k = 0; k < 16; ++k) {
        int c = lane * 16 + k;
        if (c < NCELL) {
            cellstart[batch * (NCELL + 1) + c] = excl;
            cursor[batch * NCELL + c] = excl;
            excl += local[k];
        }
    }
    if (lane == 63) cellstart[batch * (NCELL + 1) + NCELL] = s;
}

// ---------------------------------------------------------------------------
// K3: scatter vertices into cell-sorted float4(x,y,z,bitcast(id)) array.
// ---------------------------------------------------------------------------
__global__ void k3_scatter(const float* __restrict__ hs,
                           int* __restrict__ cursor,
                           float4* __restrict__ spk,
                           int n_v, int bs) {
    int t = blockIdx.x * blockDim.x + threadIdx.x;
    if (t >= bs * n_v) return;
    int b = t / n_v;
    int v = t - b * n_v;
    const float* xs = hs + (size_t)b * 6 * n_v;
    float x = xs[v], y = xs[n_v + v], z = xs[2 * n_v + v];
    int cell = cell_of(x, y, z);
    int pos = atomicAdd(&cursor[b * NCELL + cell], 1);
    spk[(size_t)b * n_v + pos] = make_float4(x, y, z, __int_as_float(v));
}

// ---------------------------------------------------------------------------
// K4: one wave per query. All <=9 (cx,cy) row ranges are loaded up-front
// (fully unrolled, independent loads -> one vmcnt wait), then lanes test
// candidates in parallel (one 16B load each). Per-lane sorted min-4 of hit
// ids, 4-round cross-lane min extraction = the 4 smallest in-radius vertex
// ids == ball-query's "first NSAMPLE in index order". Epilogue is the
// round-1 (bit-exact) loss math. NO fences / device atomics here — the
// finalize is a separate kernel (a device-scope __threadfence per wave
// compiles to a cache-wide buffer_wbl2: that was R2's 300us regression).
// ---------------------------------------------------------------------------
__global__ void k4_query(const float* __restrict__ pred,
                         const float* __restrict__ hs,
                         const float* __restrict__ un,
                         const float4* __restrict__ spk,
                         const int* __restrict__ cellstart,
                         double* __restrict__ partial,
                         float* __restrict__ pcnt,
                         int n_v, int n_pred, int bs) {
    const int lane = threadIdx.x & 63;
    const int wave = threadIdx.x >> 6;
    const int wid = blockIdx.x * 4 + wave;
    const int nq = bs * n_pred;

    float per_pt = 0.0f;
    float is_pos = 0.0f;

    if (wid < nq) {
        const int b = wid / n_pred;
        const float* xs = hs + (size_t)b * 6 * n_v;
        const float* ys = xs + n_v;
        const float* zs = xs + 2 * n_v;
        const float* unb = un + (size_t)b * n_v * 3;
        const float4* sp = spk + (size_t)b * n_v;
        const int* csb = cellstart + b * (NCELL + 1);
        const float px = pred[(size_t)wid * 3 + 0];
        const float py = pred[(size_t)wid * 3 + 1];
        const float pz = pred[(size_t)wid * 3 + 2];

        int xlo = max(0, (int)floorf((px - RPAD) * 10.0f));
        int xhi = min(9, (int)floorf((px + RPAD) * 10.0f));
        int ylo = max(0, (int)floorf((py - RPAD) * 10.0f));
        int yhi = min(9, (int)floorf((py + RPAD) * 10.0f));
        int zlo = max(0, (int)floorf((pz - RPAD) * 10.0f));
        int zhi = min(9, (int)floorf((pz + RPAD) * 10.0f));

        // Prefetch all row ranges (<=3x3 cells, z-contiguous runs). Fully
        // unrolled: 18 independent loads, clamped addresses, predicated
        // discard for out-of-window rows (no duplicate runs!).
        int rs[9], re[9];
        #pragma unroll
        for (int i = 0; i < 9; ++i) {
            int cx = xlo + i / 3;
            int cy = ylo + i % 3;
            bool valid = (cx <= xhi) && (cy <= yhi);
            int rowbase = (min(cx, 9) * 10 + min(cy, 9)) * 10;
            int lo = csb[rowbase + zlo];
            int hi = csb[rowbase + zhi + 1];
            rs[i] = valid ? lo : 0;
            re[i] = valid ? hi : 0;
        }

        int l0 = INT_MAX, l1 = INT_MAX, l2 = INT_MAX, l3 = INT_MAX;
        #pragma unroll
        for (int i = 0; i < 9; ++i) {
            for (int p = rs[i] + lane; p < re[i]; p += 64) {
                float4 c4 = sp[p];
                float dx = px - c4.x;
                float dy = py - c4.y;
                float dz = pz - c4.z;
                float d2 = dx * dx + dy * dy + dz * dz;
                if (d2 < 0.01f) {     // 0.01f == f32(0.1*0.1)
                    int vid = __float_as_int(c4.w);
                    if (vid < l3) {
                        if (vid < l1) {
                            if (vid < l0) { l3 = l2; l2 = l1; l1 = l0; l0 = vid; }
                            else          { l3 = l2; l2 = l1; l1 = vid; }
                        } else {
                            if (vid < l2) { l3 = l2; l2 = vid; }
                            else          { l3 = vid; }
                        }
                    }
                }
            }
        }

        // 4-round cross-lane min extraction (ids unique -> exactly one owner)
        int a0 = l0, a1 = l1, a2 = l2, a3 = l3;
        int s0, s1, s2, s3;
        #pragma unroll
        for (int j = 0; j < 4; ++j) {
            int m = a0;
            #pragma unroll
            for (int off = 1; off < 64; off <<= 1) m = min(m, __shfl_xor(m, off));
            if (j == 0) s0 = m; else if (j == 1) s1 = m; else if (j == 2) s2 = m; else s3 = m;
            if (a0 == m && m != INT_MAX) { a0 = a1; a1 = a2; a2 = a3; a3 = INT_MAX; }
        }
        int id0 = (s0 == INT_MAX) ? 0 : s0;      // no hits -> index 0 (ref argmax)
        int id1 = (s1 == INT_MAX) ? id0 : s1;    // unfilled -> first hit
        int id2 = (s2 == INT_MAX) ? id0 : s2;
        int id3 = (s3 == INT_MAX) ? id0 : s3;
        int ids[4] = {id0, id1, id2, id3};

        float vd[4];
        float cm = 0.0f;
        #pragma unroll
        for (int j = 0; j < 4; ++j) {
            int id = ids[j];
            float dx = px - xs[id];
            float dy = py - ys[id];
            float dz = pz - zs[id];
            float nx = unb[id * 3 + 0];
            float ny = unb[id * 3 + 1];
            float nz = unb[id * 3 + 2];
            float dot = dx * nx + dy * ny + dz * nz;
            float w = (dot >= -0.1f) ? 1.0f : 0.0f;
            float v = (dot - 0.001f) * w;
            bool msk = v < 0.0f;
            vd[j] = msk ? v : 0.0f;
            cm += msk ? 1.0f : 0.0f;
        }
        float s = ((vd[0] + vd[1]) + vd[2]) + vd[3];
        float a = s / (cm + EPSF);
        per_pt = a * a;
        is_pos = (per_pt > 0.0f) ? 1.0f : 0.0f;
    }

    __shared__ float ls[4];
    __shared__ float lc[4];
    if (lane == 0) { ls[wave] = per_pt; lc[wave] = is_pos; }
    __syncthreads();
    if (threadIdx.x == 0) {
        partial[blockIdx.x] = (double)ls[0] + (double)ls[1] + (double)ls[2] + (double)ls[3];
        pcnt[blockIdx.x] = ((lc[0] + lc[1]) + lc[2]) + lc[3];
    }
}

// ---------------------------------------------------------------------------
// K5: single-block reduction of the block partials -> final scalar loss.
// ---------------------------------------------------------------------------
__global__ void finalize_kernel(const double* __restrict__ partial,
                                const float* __restrict__ pcnt,
                                int n, float* __restrict__ out) {
    double s = 0.0, c = 0.0;
    for (int i = threadIdx.x; i < n; i += blockDim.x) {
        s += partial[i];
        c += (double)pcnt[i];
    }
    #pragma unroll
    for (int off = 32; off > 0; off >>= 1) {
        s += __shfl_down(s, off);
        c += __shfl_down(c, off);
    }
    __shared__ double ws_s[4];
    __shared__ double ws_c[4];
    int wave = threadIdx.x >> 6;
    int lane = threadIdx.x & 63;
    if (lane == 0) { ws_s[wave] = s; ws_c[wave] = c; }
    __syncthreads();
    if (threadIdx.x == 0) {
        double S = ws_s[0] + ws_s[1] + ws_s[2] + ws_s[3];
        double C = ws_c[0] + ws_c[1] + ws_c[2] + ws_c[3];
        out[0] = (float)(S / (C + 1e-7));
    }
}

extern "C" void kernel_launch(void* const* d_in, const int* in_sizes, int n_in,
                              void* d_out, int out_size, void* d_ws, size_t ws_size,
                              hipStream_t stream) {
    const float* pred    = (const float*)d_in[0];
    const float* h_state = (const float*)d_in[2];
    const int*   h_faces = (const int*)d_in[3];
    float* out = (float*)d_out;

    const int bs = 2;
    const int n_pred = in_sizes[0] / (bs * 3);   // 8192
    const int n_v    = in_sizes[2] / (bs * 6);   // 6890
    const int n_f    = in_sizes[3] / (bs * 3);   // 13776
    const int nq = bs * n_pred;                  // 16384
    const int nblk = (nq + 3) / 4;               // 4096 blocks, 4 queries each

    // ---- workspace layout (float-element offsets from d_ws) ----
    size_t o_svec    = 0;                                  // bs*n_v*3 f (zeroed)
    size_t o_scnt    = o_svec + (size_t)bs * n_v * 3;      // bs*n_v f  (zeroed)
    size_t o_counts  = o_scnt + (size_t)bs * n_v;          // bs*1000 i (zeroed)
    size_t o_zeroend = (o_counts + (size_t)bs * NCELL + 3) & ~(size_t)3;
    size_t o_cursor  = o_zeroend;                          // bs*1000 i
    size_t o_cs      = o_cursor + (size_t)bs * NCELL;      // bs*1001 i
    size_t o_partial = (o_cs + (size_t)bs * (NCELL + 1) + 1) & ~(size_t)1; // nblk d
    size_t o_pcnt    = o_partial + 2 * (size_t)nblk;       // nblk f
    size_t o_spk     = (o_pcnt + (size_t)nblk + 3) & ~(size_t)3;           // bs*n_v f4

    float* base = (float*)d_ws;
    float*  svec      = base + o_svec;
    float*  scnt      = base + o_scnt;
    int*    counts    = (int*)(base + o_counts);
    int*    cursor    = (int*)(base + o_cursor);
    int*    cellstart = (int*)(base + o_cs);
    double* partial   = (double*)(base + o_partial);
    float*  pcnt      = base + o_pcnt;
    float4* spk       = (float4*)(base + o_spk);

    // zero the accumulator zone (svec, scnt, counts) in one memset
    hipMemsetAsync(d_ws, 0, o_zeroend * sizeof(float), stream);

    int t1 = bs * n_f;   // >= bs*n_v, covers both fused jobs
    k1_face_count<<<(t1 + 255) / 256, 256, 0, stream>>>(
        h_state, h_faces, svec, scnt, counts, n_v, n_f, bs);

    int nvb = (bs * n_v + 255) / 256;
    k2_vn_scan<<<nvb + 1, 256, 0, stream>>>(
        svec, scnt, counts, cellstart, cursor, bs * n_v, nvb);

    k3_scatter<<<(bs * n_v + 255) / 256, 256, 0, stream>>>(
        h_state, cursor, spk, n_v, bs);

    k4_query<<<nblk, 256, 0, stream>>>(
        pred, h_state, svec, spk, cellstart, partial, pcnt,
        n_v, n_pred, bs);

    finalize_kernel<<<1, 256, 0, stream>>>(partial, pcnt, nblk, out);
}